// Round 1
// baseline (1627.456 us; speedup 1.0000x reference)
//
#include <hip/hip_runtime.h>
#include <hip/hip_bf16.h>
#include <stdint.h>

#define T_ 64
#define N_ 1024
#define L_ 128
#define H_ 512
#define C_ 64
#define S_ 771          // 1 + 1 + H + (L+1) + L
#define TN_ (T_*N_)

typedef unsigned short u16;
typedef unsigned int u32;
typedef float f32x4 __attribute__((ext_vector_type(4)));
typedef __bf16 bf16x8 __attribute__((ext_vector_type(8)));

__device__ __forceinline__ u16 f2bf(float f) {
  u32 u = __float_as_uint(f);
  u32 r = (u + 0x7FFFu + ((u >> 16) & 1u)) >> 16;
  return (u16)r;
}
__device__ __forceinline__ float bf2f(u16 u) {
  return __uint_as_float(((u32)u) << 16);
}
__device__ __forceinline__ void gload16(const void* g, void* l) {
  __builtin_amdgcn_global_load_lds((const __attribute__((address_space(1))) u32*)g,
                                   (__attribute__((address_space(3))) u32*)l, 16, 0, 0);
}
__device__ __forceinline__ float sigm(float x) { return 1.0f / (1.0f + __expf(-x)); }

// ---------------- prep kernels ----------------
__global__ void cast_f32_bf16(const float* __restrict__ src, u16* __restrict__ dst, int n) {
  int i = blockIdx.x * 256 + threadIdx.x;
  if (i < n) dst[i] = f2bf(src[i]);
}

// WCAT: 3 gates (r,z,n) each 512 rows x 1024 cols: [W_ih[g*512+j,:], W_hh[g*512+j,:]]
__global__ void build_wcat(const float* __restrict__ Wih, const float* __restrict__ Whh,
                           u16* __restrict__ wcat) {
  int i = blockIdx.x * 256 + threadIdx.x;
  if (i >= 3 * 512 * 1024) return;
  int g = i >> 19;
  int rem = i & 524287;
  int j = rem >> 10, k = rem & 1023;
  float v = (k < 512) ? Wih[(size_t)(g * 512 + j) * 512 + k]
                      : Whh[(size_t)(g * 512 + j) * 512 + (k - 512)];
  wcat[i] = f2bf(v);
}

__global__ void qscan(const float* __restrict__ hxs, const int* __restrict__ actions,
                      int* __restrict__ qpre, int* __restrict__ qpost) {
  int n = blockIdx.x * 256 + threadIdx.x;
  if (n >= N_) return;
  bool nz = false;
  for (int s = 0; s < S_; ++s) nz |= (hxs[(size_t)n * S_ + s] != 0.0f);
  int q = 0;
  if (nz) {  // general fallback: argmax of stored (assumed one-hot) p0
    float best = -3.4e38f;
    for (int l = 0; l < L_; ++l) {
      float v = hxs[(size_t)n * S_ + 2 + H_ + (L_ + 1) + l];
      if (v > best) { best = v; q = l; }
    }
  }
  for (int t = 0; t < T_; ++t) {
    qpre[t * N_ + n] = q;
    int a = actions[t * N_ + n];
    if (a < L_) q = a;
    qpost[t * N_ + n] = q;
  }
}

__global__ void hbf_init(const float* __restrict__ hxs, u16* __restrict__ hbf) {
  int i = blockIdx.x * 256 + threadIdx.x;
  if (i >= N_ * H_) return;
  int n = i >> 9, j = i & 511;
  hbf[i] = f2bf(hxs[(size_t)n * S_ + 2 + j]);
}

// A = [cond_t | emb[lines[n, qpre]]] as bf16 (TN x 576); one wave per row
__global__ void build_abuf(const float* __restrict__ cond, const float* __restrict__ emb,
                           const int* __restrict__ lines, const int* __restrict__ qpre,
                           u16* __restrict__ abuf) {
  int row = blockIdx.x * 4 + (threadIdx.x >> 6);
  int lane = threadIdx.x & 63;
  int n = row & (N_ - 1);
  int q = qpre[row];
  int line = lines[n * L_ + q];
  abuf[(size_t)row * 576 + lane] = f2bf(cond[(size_t)row * 64 + lane]);
  const float* er = emb + (size_t)line * H_;
  u16* ar = abuf + (size_t)row * 576 + 64;
  for (int j = lane; j < H_; j += 64) ar[j] = f2bf(er[j]);
}

// ---------------- phase-A GEMM (m97-style 128x128, BK=64, NT, bias+relu, bf16 out) ----------------
#define BM 128
#define BN 128
#define BK 64
__global__ __launch_bounds__(256) void gemm_nt(
    const u16* __restrict__ A, int lda,
    const u16* __restrict__ B, int ldb,
    const float* __restrict__ bias,
    u16* __restrict__ C, int ldc,
    int K, int relu)
{
  __shared__ __align__(16) u16 lA[BM * BK];
  __shared__ __align__(16) u16 lB[BN * BK];
  int tid = threadIdx.x;
  int lane = tid & 63;
  int wave = tid >> 6;
  int wm = wave >> 1, wn = wave & 1;
  int m0 = blockIdx.y * BM;
  int n0 = blockIdx.x * BN;

  f32x4 acc[4][4];
  f32x4 zero = {0.f, 0.f, 0.f, 0.f};
#pragma unroll
  for (int i = 0; i < 4; ++i)
#pragma unroll
    for (int j = 0; j < 4; ++j) acc[i][j] = zero;

  int nkt = K / BK;
  for (int kt = 0; kt < nkt; ++kt) {
#pragma unroll
    for (int it = 0; it < 4; ++it) {
      int s = it * 256 + tid;
      int row = s >> 3, cs = s & 7;
      gload16(A + (size_t)(m0 + row) * lda + kt * BK + cs * 8,
              lA + (size_t)(it * 256 + (tid & ~63)) * 8);
      gload16(B + (size_t)(n0 + row) * ldb + kt * BK + cs * 8,
              lB + (size_t)(it * 256 + (tid & ~63)) * 8);
    }
    __syncthreads();
#pragma unroll
    for (int ks = 0; ks < 2; ++ks) {
      bf16x8 af[4], bfr[4];
#pragma unroll
      for (int fm = 0; fm < 4; ++fm) {
        int rowa = wm * 64 + fm * 16 + (lane & 15);
        af[fm] = *(const bf16x8*)&lA[rowa * BK + ks * 32 + ((lane >> 4) << 3)];
      }
#pragma unroll
      for (int fn = 0; fn < 4; ++fn) {
        int rowb = wn * 64 + fn * 16 + (lane & 15);
        bfr[fn] = *(const bf16x8*)&lB[rowb * BK + ks * 32 + ((lane >> 4) << 3)];
      }
#pragma unroll
      for (int fm = 0; fm < 4; ++fm)
#pragma unroll
        for (int fn = 0; fn < 4; ++fn)
          acc[fm][fn] = __builtin_amdgcn_mfma_f32_16x16x32_bf16(af[fm], bfr[fn], acc[fm][fn], 0, 0, 0);
    }
    __syncthreads();
  }
#pragma unroll
  for (int fm = 0; fm < 4; ++fm) {
#pragma unroll
    for (int fn = 0; fn < 4; ++fn) {
      int col = n0 + wn * 64 + fn * 16 + (lane & 15);
      float b = bias[col];
#pragma unroll
      for (int v = 0; v < 4; ++v) {
        int row = m0 + wm * 64 + fm * 16 + ((lane >> 4) << 2) + v;
        float val = acc[fm][fn][v] + b;
        if (relu) val = fmaxf(val, 0.0f);
        C[(size_t)row * ldc + col] = f2bf(val);
      }
    }
  }
}

// ---------------- phase-B: fused GRU step ----------------
// Output tile: 64 rows(n) x 32 cols(j) x {R,Z,Npart}; grid (16 jt, 16 mt) = 256 WGs.
// K = 1024: first 512 from X3 (accN -> i_n), last 512 from Hbf (accN -> h_n).
__device__ __forceinline__ void gru_stage(const u16* __restrict__ Asrc, int akcol,
                                          const u16* __restrict__ WCAT, int j0, int bkcol,
                                          u16* lA, u16* lB, int tid)
{
#pragma unroll
  for (int it = 0; it < 2; ++it) {
    int s = it * 256 + tid;
    int row = s >> 3, cs = s & 7;
    gload16(Asrc + (size_t)row * 512 + akcol + cs * 8,
            lA + (size_t)(it * 256 + (tid & ~63)) * 8);
  }
#pragma unroll
  for (int g = 0; g < 3; ++g) {
    int row = tid >> 3, cs = tid & 7;
    gload16(WCAT + ((size_t)g << 19) + (size_t)(j0 + row) * 1024 + bkcol + cs * 8,
            lB + (size_t)(g * 256 + (tid & ~63)) * 8);
  }
}

__device__ __forceinline__ void gru_compute(const u16* lA, const u16* lB, int lane, int wave,
                                            f32x4* accR, f32x4* accZ, f32x4* accN)
{
#pragma unroll
  for (int ks = 0; ks < 2; ++ks) {
    int rowa = wave * 16 + (lane & 15);
    bf16x8 a = *(const bf16x8*)&lA[rowa * 64 + ks * 32 + ((lane >> 4) << 3)];
#pragma unroll
    for (int fn = 0; fn < 2; ++fn) {
      int rowb = fn * 16 + (lane & 15);
      int boff = rowb * 64 + ks * 32 + ((lane >> 4) << 3);
      bf16x8 bR = *(const bf16x8*)&lB[boff];
      bf16x8 bZ = *(const bf16x8*)&lB[2048 + boff];
      bf16x8 bN = *(const bf16x8*)&lB[4096 + boff];
      accR[fn] = __builtin_amdgcn_mfma_f32_16x16x32_bf16(a, bR, accR[fn], 0, 0, 0);
      accZ[fn] = __builtin_amdgcn_mfma_f32_16x16x32_bf16(a, bZ, accZ[fn], 0, 0, 0);
      accN[fn] = __builtin_amdgcn_mfma_f32_16x16x32_bf16(a, bN, accN[fn], 0, 0, 0);
    }
  }
}

__global__ __launch_bounds__(256) void gru_step(
    const u16* __restrict__ X3,      // (TN,512) bf16
    const u16* __restrict__ Hbf,     // (N,512) bf16 h_{t-1}
    u16* __restrict__ HbfOut,        // (N,512) bf16 h_t
    const float* __restrict__ Hprev, // f32 h_{t-1}, row stride hstride
    int hstride,
    const u16* __restrict__ WCAT,
    const float* __restrict__ bih, const float* __restrict__ bhh,
    float* __restrict__ out, int t)
{
  __shared__ __align__(16) u16 lA[64 * 64];
  __shared__ __align__(16) u16 lB[3 * 32 * 64];
  int tid = threadIdx.x;
  int lane = tid & 63;
  int wave = tid >> 6;
  int mt = blockIdx.y, jt = blockIdx.x;
  int n0 = mt * 64, j0 = jt * 32;

  f32x4 zero = {0.f, 0.f, 0.f, 0.f};
  f32x4 accR[2] = {zero, zero}, accZ[2] = {zero, zero};
  f32x4 accNi[2] = {zero, zero}, accNh[2] = {zero, zero};

  const size_t tb = (size_t)t * N_;
  const u16* A0 = X3 + (tb + n0) * 512;
  const u16* A1 = Hbf + (size_t)n0 * 512;

  for (int kt = 0; kt < 8; ++kt) {
    gru_stage(A0, kt * 64, WCAT, j0, kt * 64, lA, lB, tid);
    __syncthreads();
    gru_compute(lA, lB, lane, wave, accR, accZ, accNi);
    __syncthreads();
  }
  for (int kt = 8; kt < 16; ++kt) {
    gru_stage(A1, (kt - 8) * 64, WCAT, j0, kt * 64, lA, lB, tid);
    __syncthreads();
    gru_compute(lA, lB, lane, wave, accR, accZ, accNh);
    __syncthreads();
  }

#pragma unroll
  for (int fn = 0; fn < 2; ++fn) {
    int j = j0 + fn * 16 + (lane & 15);
    float brj = bih[j] + bhh[j];
    float bzj = bih[512 + j] + bhh[512 + j];
    float bnij = bih[1024 + j];
    float bnhj = bhh[1024 + j];
#pragma unroll
    for (int v = 0; v < 4; ++v) {
      int n = n0 + wave * 16 + ((lane >> 4) << 2) + v;
      float r = sigm(accR[fn][v] + brj);
      float z = sigm(accZ[fn][v] + bzj);
      float nn = tanhf(accNi[fn][v] + bnij + r * (accNh[fn][v] + bnhj));
      float hold = Hprev[(size_t)n * hstride + j];
      float hnew = (1.0f - z) * nn + z * hold;
      out[(tb + n) * S_ + 2 + j] = hnew;
      HbfOut[(size_t)n * 512 + j] = f2bf(hnew);
    }
  }
}

// ---------------- phase-C: heads + probs + p, batched over all (t,n) ----------------
__global__ __launch_bounds__(256) void heads_kernel(
    const float* __restrict__ Wc, const float* __restrict__ bc,
    const float* __restrict__ Wa, const float* __restrict__ ba,
    const int* __restrict__ actions, const int* __restrict__ qpre,
    const int* __restrict__ qpost, float* __restrict__ out)
{
  int row = blockIdx.x * 4 + (threadIdx.x >> 6);
  int lane = threadIdx.x & 63;
  const float* h = out + (size_t)row * S_ + 2;
  float pc = 0, p0 = 0, p1 = 0, p2 = 0, p3 = 0;
#pragma unroll
  for (int jj = 0; jj < 8; ++jj) {
    int k = lane * 8 + jj;
    float hv = h[k];
    pc += hv * Wc[k];
    p0 += hv * Wa[k];
    p1 += hv * Wa[512 + k];
    p2 += hv * Wa[1024 + k];
    p3 += hv * Wa[1536 + k];
  }
#pragma unroll
  for (int m = 1; m < 64; m <<= 1) {
    pc += __shfl_xor(pc, m);
    p0 += __shfl_xor(p0, m);
    p1 += __shfl_xor(p1, m);
    p2 += __shfl_xor(p2, m);
    p3 += __shfl_xor(p3, m);
  }
  float v = pc + bc[0];
  float k0 = p0 + ba[0], k1 = p1 + ba[1], k2 = p2 + ba[2], k3 = p3 + ba[3];
  float mx = fmaxf(k0, fmaxf(k1, k2));
  float e0 = __expf(k0 - mx), e1 = __expf(k1 - mx), e2 = __expf(k2 - mx);
  float es = e0 + e1 + e2;
  float l0 = e0 / es, l1 = e1 / es, l2 = e2 / es;
  float no = sigm(k3);
  float total = (1.0f - no) * (l0 + l1 + l2) + no;
  float sc = (1.0f - no) / total;
  int q = qpre[row], qp = qpost[row];
  int a = actions[row];
  if (lane == 0) {
    out[(size_t)row * S_] = (float)a;
    out[(size_t)row * S_ + 1] = v;
  }
  float* pr = out + (size_t)row * S_ + 2 + H_;
  for (int c = lane; c < L_ + 1; c += 64) {
    float val;
    if (c == L_) val = no / total;
    else {
      val = 0.f;
      if (q == 0)            { if (c == 0) val = l1 + l2; else if (c == 1) val = l0; }
      else if (q == L_ - 1)  { if (c == L_ - 2) val = l2; else if (c == L_ - 1) val = l0 + l1; }
      else                   { if (c == q - 1) val = l2; else if (c == q) val = l1; else if (c == q + 1) val = l0; }
      val *= sc;
    }
    pr[c] = val;
  }
  float* pp = pr + (L_ + 1);
  for (int c = lane; c < L_; c += 64) pp[c] = (c == qp) ? 1.0f : 0.0f;
}

__global__ void copy_last(float* __restrict__ out) {
  int i = blockIdx.x * 256 + threadIdx.x;
  if (i < N_ * S_) out[(size_t)TN_ * S_ + i] = out[(size_t)(T_ - 1) * N_ * S_ + i];
}

// ---------------- launch ----------------
extern "C" void kernel_launch(void* const* d_in, const int* in_sizes, int n_in,
                              void* d_out, int out_size, void* d_ws, size_t ws_size,
                              hipStream_t stream) {
  const float* cond = (const float*)d_in[0];
  const float* hxs  = (const float*)d_in[1];
  const float* emb  = (const float*)d_in[2];
  const float* W0   = (const float*)d_in[3];
  const float* b0   = (const float*)d_in[4];
  const float* W1   = (const float*)d_in[5];
  const float* b1   = (const float*)d_in[6];
  const float* W2   = (const float*)d_in[7];
  const float* b2   = (const float*)d_in[8];
  const float* Wih  = (const float*)d_in[9];
  const float* bih  = (const float*)d_in[10];
  const float* Whh  = (const float*)d_in[11];
  const float* bhh  = (const float*)d_in[12];
  const float* Wc   = (const float*)d_in[13];
  const float* bc   = (const float*)d_in[14];
  const float* Wa   = (const float*)d_in[15];
  const float* ba   = (const float*)d_in[16];
  const int* lines   = (const int*)d_in[17];
  const int* actions = (const int*)d_in[18];
  float* out = (float*)d_out;

  char* ws = (char*)d_ws;
  size_t off = 0;
  auto alloc = [&](size_t bytes) {
    char* p = ws + off;
    off += (bytes + 255) & ~(size_t)255;
    return p;
  };
  // Region P (75.5MB): Abuf, later reused for X2. Region Q (67MB): X1, later X3.
  u16* P = (u16*)alloc((size_t)TN_ * 576 * 2);
  u16* Q = (u16*)alloc((size_t)TN_ * 512 * 2);
  u16* Abuf = P;
  u16* X1 = Q;
  u16* X2 = P;
  u16* X3 = Q;
  u16* W0b = (u16*)alloc((size_t)512 * 576 * 2);
  u16* W1b = (u16*)alloc((size_t)512 * 512 * 2);
  u16* W2b = (u16*)alloc((size_t)512 * 512 * 2);
  u16* WCAT = (u16*)alloc((size_t)3 * 512 * 1024 * 2);
  int* qpre  = (int*)alloc((size_t)TN_ * 4);
  int* qpost = (int*)alloc((size_t)TN_ * 4);
  u16* hb0 = (u16*)alloc((size_t)N_ * 512 * 2);
  u16* hb1 = (u16*)alloc((size_t)N_ * 512 * 2);

  cast_f32_bf16<<<(512 * 576 + 255) / 256, 256, 0, stream>>>(W0, W0b, 512 * 576);
  cast_f32_bf16<<<(512 * 512 + 255) / 256, 256, 0, stream>>>(W1, W1b, 512 * 512);
  cast_f32_bf16<<<(512 * 512 + 255) / 256, 256, 0, stream>>>(W2, W2b, 512 * 512);
  build_wcat<<<(3 * 512 * 1024 + 255) / 256, 256, 0, stream>>>(Wih, Whh, WCAT);
  qscan<<<4, 256, 0, stream>>>(hxs, actions, qpre, qpost);
  hbf_init<<<(N_ * 512 + 255) / 256, 256, 0, stream>>>(hxs, hb0);
  build_abuf<<<TN_ / 4, 256, 0, stream>>>(cond, emb, lines, qpre, Abuf);

  gemm_nt<<<dim3(4, 512), 256, 0, stream>>>(Abuf, 576, W0b, 576, b0, X1, 512, 576, 1);
  gemm_nt<<<dim3(4, 512), 256, 0, stream>>>(X1, 512, W1b, 512, b1, X2, 512, 512, 1);
  gemm_nt<<<dim3(4, 512), 256, 0, stream>>>(X2, 512, W2b, 512, b2, X3, 512, 512, 1);

  for (int t = 0; t < T_; ++t) {
    const u16* hin = (t & 1) ? hb1 : hb0;
    u16* hout = (t & 1) ? hb0 : hb1;
    const float* hprev = (t == 0) ? (hxs + 2) : (out + (size_t)(t - 1) * N_ * S_ + 2);
    gru_step<<<dim3(16, 16), 256, 0, stream>>>(X3, hin, hout, hprev, S_, WCAT, bih, bhh, out, t);
  }

  heads_kernel<<<TN_ / 4, 256, 0, stream>>>(Wc, bc, Wa, ba, actions, qpre, qpost, out);
  copy_last<<<(N_ * S_ + 255) / 256, 256, 0, stream>>>(out);
}